// Round 5
// baseline (264.640 us; speedup 1.0000x reference)
//
#include <hip/hip_runtime.h>

#define BB 32
#define TT 2000
#define NG 500          // float4 groups per alphas row
#define NW 63           // 32-step fire-mask words (62 full + 1 partial)
#define HH 512
#define LL 256
#define THRESH 0.95f

// d_ws layout:
//   int2  rec[BB*LL]  : per-fire {t, bits(dist)}  (rem recomputed as a*sc-dist)
//   int   nfires[BB]
//   float scale[BB]

__global__ __launch_bounds__(256) void cif_scan_kernel(
    const float* __restrict__ alphas, const int* __restrict__ tlen,
    int2* __restrict__ rec, int* __restrict__ nfires,
    float* __restrict__ scale_g)
{
    const int b = blockIdx.x;
    const int tid = threadIdx.x;
    __shared__ float sa[TT];         // scaled alphas
    __shared__ float sinteg[TT];     // post-reset integ per step
    __shared__ double red[256];
    __shared__ unsigned smask[NW];
    __shared__ int spre[NW + 1];     // exclusive prefix of fire counts
    __shared__ float s_scale;

    // ---- Phase 1: load row -> LDS + f64 row sum (identical grouping to the
    // passing R4 kernel; f64 slack makes the f32-rounded sum bit-stable). ----
    const float4* a4 = (const float4*)(alphas + b * TT);
    float4* sa4 = (float4*)sa;
    double s = 0.0;
    for (int g = tid; g < NG; g += 256) {
        float4 v = a4[g];
        sa4[g] = v;
        s += (double)v.x + (double)v.y + (double)v.z + (double)v.w;
    }
    red[tid] = s;
    __syncthreads();
    for (int off = 128; off > 0; off >>= 1) {
        if (tid < off) red[tid] += red[tid + off];
        __syncthreads();
    }
    if (tid == 0) {
        const float sumf = (float)red[0];
        const float sc = (float)tlen[b] / sumf;   // f32 divide, as reference
        s_scale = sc;
        scale_g[b] = sc;
    }
    __syncthreads();
    const float sc = s_scale;

    // ---- Phase 2: pre-scale in parallel (same f32 mul the gather redoes). ----
    for (int g = tid; g < NG; g += 256) {
        float4 v = sa4[g];
        v.x *= sc; v.y *= sc; v.z *= sc; v.w *= sc;
        sa4[g] = v;
    }
    __syncthreads();

    // ---- Phase 3: branchless serial scan on thread 0. Per step:
    // add -> cmp -> cndmask (12-cyc chain). Outputs: integ_post (b128/4 steps)
    // and fire bits (one b32 per 32 steps). No branches, no scattered stores. ----
    if (tid == 0) {
        const float4* s4 = (const float4*)sa;
        float4* ip4 = (float4*)sinteg;
        float integ = 0.0f;
        unsigned mask = 0;
        float4 buf[8];                       // 32-step prefetch pipeline
        #pragma unroll
        for (int i = 0; i < 8; ++i) buf[i] = s4[i];

        for (int w = 0; w < 62; ++w) {       // 62 full words = 1984 steps
            #pragma unroll
            for (int i = 0; i < 8; ++i) {
                const int g = w * 8 + i;
                const float4 c = buf[i];
                if (g + 8 < NG) buf[i] = s4[g + 8];
                const float av[4] = {c.x, c.y, c.z, c.w};
                float iv[4];
                #pragma unroll
                for (int j = 0; j < 4; ++j) {
                    const float a = av[j];
                    float ii = integ + a;              // integrate += alpha
                    const bool fire = (ii >= THRESH);
                    const float iim1 = ii - 1.0f;      // off-chain vs cmp
                    ii = fire ? iim1 : ii;             // cndmask
                    mask |= fire ? (1u << (i * 4 + j)) : 0u;  // const bit
                    iv[j] = ii;
                    integ = ii;
                }
                ip4[g] = make_float4(iv[0], iv[1], iv[2], iv[3]);
            }
            smask[w] = mask;
            mask = 0;
        }
        #pragma unroll
        for (int i = 0; i < 4; ++i) {        // tail: steps 1984..1999
            const int g = 496 + i;
            const float4 c = buf[i];
            const float av[4] = {c.x, c.y, c.z, c.w};
            float iv[4];
            #pragma unroll
            for (int j = 0; j < 4; ++j) {
                const float a = av[j];
                float ii = integ + a;
                const bool fire = (ii >= THRESH);
                const float iim1 = ii - 1.0f;
                ii = fire ? iim1 : ii;
                mask |= fire ? (1u << (i * 4 + j)) : 0u;
                iv[j] = ii;
                integ = ii;
            }
            ip4[g] = make_float4(iv[0], iv[1], iv[2], iv[3]);
        }
        smask[62] = mask;
    }
    __syncthreads();

    // ---- Phase 4: parallel fire extraction. ----
    if (tid == 0) {                          // 63 trivial adds
        int r = 0;
        for (int w = 0; w < NW; ++w) { spre[w] = r; r += __popc(smask[w]); }
        spre[NW] = r;
        nfires[b] = (r < LL) ? r : LL;
    }
    __syncthreads();
    if (tid < NW) {
        unsigned m = smask[tid];
        int tok = spre[tid];
        while (m) {
            const int j = __ffs(m) - 1;
            m &= m - 1;
            const int t = tid * 32 + j;
            if (tok < LL) {
                const float dist = (t == 0) ? 1.0f : (1.0f - sinteg[t - 1]);
                int2 r; r.x = t; r.y = __float_as_int(dist);
                rec[b * LL + tok] = r;
            }
            ++tok;
        }
    }
}

__global__ __launch_bounds__(128) void cif_gather_kernel(
    const float* __restrict__ hidden, const float* __restrict__ alphas,
    const float* __restrict__ scale_g, const int2* __restrict__ rec,
    const int* __restrict__ nfires, float* __restrict__ out)
{
    const int l = blockIdx.x;       // token index
    const int b = blockIdx.y;       // batch
    const int tid = threadIdx.x;    // 128 threads x float4 = 512 = HH

    float4 acc = make_float4(0.f, 0.f, 0.f, 0.f);
    const int F = nfires[b];
    if (l < F) {
        const int2 re = rec[b * LL + l];
        const int e = re.x;                        // fire step of this token
        const float dist = __int_as_float(re.y);   // weight of frame e
        const float sc = scale_g[b];
        const float* hb = hidden + (size_t)b * TT * HH + (size_t)tid * 4;
        const float* ab = alphas + b * TT;
        int t0 = 0;
        if (l > 0) {
            const int2 rp = rec[b * LL + l - 1];
            const int sp = rp.x;
            const float dp = __int_as_float(rp.y);
            const float rem = ab[sp] * sc - dp;    // a - cur, bit-exact
            const float4 hv = *(const float4*)(hb + (size_t)sp * HH);
            acc.x = rem * hv.x; acc.y = rem * hv.y;
            acc.z = rem * hv.z; acc.w = rem * hv.w;
            t0 = sp + 1;
        }
        // Ascending t (reference order), depth-2 load pipeline; interior
        // weight = alphas[t]*sc (bit-identical to scan), dist at t==e.
        int t = t0;
        float w0 = (t < e) ? ab[t] * sc : dist;
        float4 h0 = *(const float4*)(hb + (size_t)t * HH);
        if (t < e) {
            float w1 = (t + 1 < e) ? ab[t + 1] * sc : dist;
            float4 h1 = *(const float4*)(hb + (size_t)(t + 1) * HH);
            while (t + 2 <= e) {
                const float w2 = (t + 2 < e) ? ab[t + 2] * sc : dist;
                const float4 h2 = *(const float4*)(hb + (size_t)(t + 2) * HH);
                acc.x += w0 * h0.x; acc.y += w0 * h0.y;
                acc.z += w0 * h0.z; acc.w += w0 * h0.w;
                w0 = w1; h0 = h1; w1 = w2; h1 = h2; ++t;
            }
            acc.x += w0 * h0.x; acc.y += w0 * h0.y;
            acc.z += w0 * h0.z; acc.w += w0 * h0.w;
            w0 = w1; h0 = h1;
        }
        acc.x += w0 * h0.x; acc.y += w0 * h0.y;
        acc.z += w0 * h0.z; acc.w += w0 * h0.w;
    }
    *(float4*)(out + ((size_t)b * LL + l) * HH + (size_t)tid * 4) = acc;
}

extern "C" void kernel_launch(void* const* d_in, const int* in_sizes, int n_in,
                              void* d_out, int out_size, void* d_ws, size_t ws_size,
                              hipStream_t stream) {
    const float* hidden = (const float*)d_in[0];   // [B,T,H] f32
    const float* alphas = (const float*)d_in[1];   // [B,T]   f32
    const int*   tlen   = (const int*)d_in[2];     // [B]     i32
    float* out = (float*)d_out;                    // [B,L,H] f32

    int2*  rec     = (int2*)d_ws;
    int*   nfires  = (int*)(rec + BB * LL);
    float* scale_g = (float*)(nfires + BB);

    cif_scan_kernel<<<BB, 256, 0, stream>>>(alphas, tlen, rec, nfires, scale_g);
    cif_gather_kernel<<<dim3(LL, BB), 128, 0, stream>>>(hidden, alphas, scale_g,
                                                        rec, nfires, out);
}